// Round 20
// baseline (56.869 us; speedup 1.0000x reference)
//
#include <hip/hip_runtime.h>

// Conv2D 3x3 VALID NHWC, B=16 H=W=224 C=32 F=32 -> [16,222,222,32] fp32.
// Round 20: cross-round occupancy synthesis: at ~128 VGPR only 3 wave-slots
// per SIMD exist (~480 usable / 128-granule), so a 2nd 512/384-thr block
// (needs 2+ slots/SIMD) never co-resides -> R12/R16/R18/R19 all ran 1
// block/CU regardless of LDS. Fix: 4-wave (256-thr) blocks need 1 slot/SIMD
// -> 3 blocks/CU dock at 128 VGPR.
//  - (256,2): VGPR cap 256 (fixes R17's 84-cap spill), expect ~126 used.
//  - ring-3 x 64-col: 50.7 KB/block, 3 x 50.7 = 152.1 KB exact LDS fit.
//  - full 36-MFMA rows (fixes R16); grid 768 = 3/CU exactly, 8 XCDs x 96,
//    zero tail (fixes R18/R19). Row strips 5/4: 30x5 + 18x4 = 222.

#define HO 222
#define WO 222
#define HIN 224
#define WIN 224
#define CIN 32
#define FOUT 32

#define WROWB 4224            // 66 px * 64 B bf16 (conflict-free layout)
#define WAVELDS (3 * WROWB)   // ring-3: 12672 B/wave -> block 50688 B
#define NSG 9                 // stage granule-iters (528/64 -> 9, clamped)

typedef __attribute__((ext_vector_type(8))) short short8;
typedef __attribute__((ext_vector_type(4))) float float4v;

__device__ inline short f2bf(float f) {                  // RNE (weights only)
    unsigned u = __builtin_bit_cast(unsigned, f);
    unsigned r = (u + 0x7FFFu + ((u >> 16) & 1u)) >> 16;
    return (short)r;
}

__global__ __launch_bounds__(256, 2) void conv3x3_wave(
    const float* __restrict__ x,     // [16,224,224,32]
    const float* __restrict__ w,     // [32][288 = (kh,kw,c)]
    const float* __restrict__ bias,  // [32]
    float* __restrict__ out)         // [16,222,222,32]
{
    __shared__ uint4 lds_all[4 * WAVELDS / 16];          // 50688 B -> 3 blocks/CU
    const int tid  = threadIdx.x;
    const int lane = tid & 63;
    const int wave = tid >> 6;                           // 0..3
    char* wbase = reinterpret_cast<char*>(lds_all) + wave * WAVELDS;

    const int fcol = lane & 15;            // A row (filter) / D col (pixel)
    const int kq   = lane >> 4;            // k-slice: channels kq*8..+7

    // ---- weights -> register A-fragments ----
    short8 bfr[2][9];
#pragma unroll
    for (int h = 0; h < 2; ++h) {
        const float* wf = w + (h * 16 + fcol) * 288 + kq * 8;
#pragma unroll
        for (int s = 0; s < 9; ++s) {
            float4 lo = reinterpret_cast<const float4*>(wf + s * 32)[0];
            float4 hi = reinterpret_cast<const float4*>(wf + s * 32)[1];
            short8 v;
            v[0] = f2bf(lo.x); v[1] = f2bf(lo.y); v[2] = f2bf(lo.z); v[3] = f2bf(lo.w);
            v[4] = f2bf(hi.x); v[5] = f2bf(hi.y); v[6] = f2bf(hi.z); v[7] = f2bf(hi.w);
            bfr[h][s] = v;
        }
    }
    const float4 bias0 = reinterpret_cast<const float4*>(bias)[kq];
    const float4 bias1 = reinterpret_cast<const float4*>(bias)[4 + kq];

    // ---- bijective XCD remap: nwg = 768 = 8 * 96 ----
    const int orig = blockIdx.x;
    const int wid  = (orig & 7) * 96 + (orig >> 3);

    // wave-strip id; rst fastest -> vertical neighbors contiguous on one XCD
    const int W    = wid * 4 + wave;       // 0..3071
    const int b    = W / 192;              // 4 colstrips * 48 rowstrips
    const int rem  = W - b * 192;
    const int cst  = rem / 48;             // 0..3
    const int rst  = rem - cst * 48;       // 0..47
    const int c0   = cst * 64;
    const int nrows = (rst < 30) ? 5 : 4;  // 30*5 + 18*4 = 222
    const int gr0   = (rst < 30) ? 5 * rst : 150 + 4 * (rst - 30);
    const int nck  = (cst < 3) ? 4 : 2;    // cst=3 covers cols 192..221

    float4 sv[NSG];                        // stage registers (const-indexed)

#define SLOAD(RR)                                                             \
    {                                                                         \
        const int ir_ = gr0 + (RR);       /* <= gr0+nrows+1 <= 223 */         \
        _Pragma("unroll")                                                     \
        for (int i_ = 0; i_ < NSG; ++i_) {                                    \
            int g_ = lane + 64 * i_; if (g_ > 527) g_ = 527;                  \
            int px_ = g_ >> 3, sub_ = g_ & 7;                                 \
            int ic_ = c0 + px_; if (ic_ > WIN - 1) ic_ = WIN - 1;             \
            sv[i_] = *reinterpret_cast<const float4*>(                        \
                x + ((b * HIN + ir_) * WIN + ic_) * CIN + sub_ * 4);          \
        }                                                                     \
    }

#define SWRITE(SLOT)                                                          \
    {                                                                         \
        char* sb_ = wbase + (SLOT) * WROWB;                                   \
        _Pragma("unroll")                                                     \
        for (int i_ = 0; i_ < NSG; ++i_) {                                    \
            int g_ = lane + 64 * i_; if (g_ > 527) g_ = 527;                  \
            int px_ = g_ >> 3, sub_ = g_ & 7;                                 \
            uint4 u_ = __builtin_bit_cast(uint4, sv[i_]);                     \
            uint2 p_;                                                         \
            p_.x = __builtin_amdgcn_perm(u_.y, u_.x, 0x07060302u);            \
            p_.y = __builtin_amdgcn_perm(u_.w, u_.z, 0x07060302u);            \
            *reinterpret_cast<uint2*>(sb_ + px_ * 64 + sub_ * 8) = p_;        \
        }                                                                     \
    }

    // ---------- prologue: rows 0,1,2 -> slots 0,1,2 ----------
    SLOAD(0); SWRITE(0);
    SLOAD(1); SWRITE(1);
    SLOAD(2); SWRITE(2);

    // ---------- barrier-free main loop (nrows = 4 or 5, wave-uniform) ----------
    int rm = 0;                            // r % 3
#pragma unroll 1
    for (int r = 0; r < nrows; ++r) {
        if (r < nrows - 1) SLOAD(r + 3);             // next row in flight
        __builtin_amdgcn_sched_barrier(0);

        const int ho = gr0 + r;                      // < 222 by construction
#pragma unroll
        for (int ck = 0; ck < 4; ++ck) {
            if (ck < nck) {
                float4v acc0 = {0.f, 0.f, 0.f, 0.f};
                float4v acc1 = {0.f, 0.f, 0.f, 0.f};
#pragma unroll
                for (int s = 0; s < 9; ++s) {
                    const int kh = s / 3, kw = s % 3;
                    int slot = rm + kh; if (slot >= 3) slot -= 3;
                    const short8 a = *reinterpret_cast<const short8*>(
                        wbase + slot * WROWB + (ck * 16 + fcol + kw) * 64 + kq * 16);
                    acc0 = __builtin_amdgcn_mfma_f32_16x16x32_bf16(bfr[0][s], a, acc0, 0, 0, 0);
                    acc1 = __builtin_amdgcn_mfma_f32_16x16x32_bf16(bfr[1][s], a, acc1, 0, 0, 0);
                }
                // D[filter][pixel]: col(lane&15)=pixel, row=kq*4+r=filter
                const int wo = c0 + ck * 16 + fcol;
                if (wo < WO) {
                    float* o = out + ((b * HO + ho) * WO + wo) * FOUT;
                    float4 v0 = {acc0[0] + bias0.x, acc0[1] + bias0.y,
                                 acc0[2] + bias0.z, acc0[3] + bias0.w};
                    float4 v1 = {acc1[0] + bias1.x, acc1[1] + bias1.y,
                                 acc1[2] + bias1.z, acc1[3] + bias1.w};
                    reinterpret_cast<float4*>(o)[kq]     = v0;
                    reinterpret_cast<float4*>(o)[4 + kq] = v1;
                }
            }
        }

        __builtin_amdgcn_sched_barrier(0);
        // row r+3 -> slot r%3 (row r fully consumed; in-wave DS order)
        if (r < nrows - 1) SWRITE(rm);

        rm += 1; if (rm == 3) rm = 0;
    }
}

extern "C" void kernel_launch(void* const* d_in, const int* in_sizes, int n_in,
                              void* d_out, int out_size, void* d_ws, size_t ws_size,
                              hipStream_t stream) {
    const float* x    = (const float*)d_in[0];
    const float* w    = (const float*)d_in[1];
    const float* bias = (const float*)d_in[2];
    float* out        = (float*)d_out;

    conv3x3_wave<<<dim3(768), dim3(256), 0, stream>>>(x, w, bias, out);
}

// Round 21
// 48.011 us; speedup vs baseline: 1.1845x; 1.1845x over previous
//
#include <hip/hip_runtime.h>

// Conv2D 3x3 VALID NHWC, B=16 H=W=224 C=32 F=32 -> [16,222,222,32] fp32.
// Round 21: R15 (depth-2 staging, two named reg sets) failed ONLY because
// __launch_bounds__(512,1) still capped VGPR at 128 -> 144-reg working set
// spilled (WRITE 105.7 MB). R16-R20 chased occupancy via an unreliable
// gfx950 OccupancyPercent counter and all regressed; R14 (depth-1, 45.6us)
// remains best. This round: R15 verbatim with SINGLE-ARG launch_bounds(512)
// -- no min-waves constraint, allocator free to use up to 256 VGPR at the
// 2 waves/SIMD R14 already runs. Same TLP, 2x prefetch depth, no spill.
// Decisive counters: VGPR 160-220 & WRITE ~98.5 MB => depth-2 properly
// tested; dur <45.6 => latency-cover theory confirmed.

#define HO 222
#define WO 222
#define HIN 224
#define WIN 224
#define CIN 32
#define FOUT 32

#define RPW 7                 // output rows per wave-strip
#define WROWB 4224            // 66 px * 64 B bf16 (unpadded -- conflict-free)
#define WAVELDS 16896         // 4 ring slots
#define NSG 9                 // stage granule-iters per lane

typedef __attribute__((ext_vector_type(8))) short short8;
typedef __attribute__((ext_vector_type(4))) float float4v;

__device__ inline short f2bf(float f) {                  // RNE (weights only)
    unsigned u = __builtin_bit_cast(unsigned, f);
    unsigned r = (u + 0x7FFFu + ((u >> 16) & 1u)) >> 16;
    return (short)r;
}

__global__ __launch_bounds__(512) void conv3x3_wave(
    const float* __restrict__ x,     // [16,224,224,32]
    const float* __restrict__ w,     // [32][288 = (kh,kw,c)]
    const float* __restrict__ bias,  // [32]
    float* __restrict__ out)         // [16,222,222,32]
{
    __shared__ uint4 lds_all[8 * WAVELDS / 16];          // 135168 B
    const int tid  = threadIdx.x;
    const int lane = tid & 63;
    const int wave = tid >> 6;                           // 0..7
    char* wbase = reinterpret_cast<char*>(lds_all) + wave * WAVELDS;

    const int fcol = lane & 15;            // A row (filter) / D col (pixel)
    const int kq   = lane >> 4;            // k-slice: channels kq*8..+7

    // ---- weights -> register A-fragments ----
    short8 bfr[2][9];
#pragma unroll
    for (int h = 0; h < 2; ++h) {
        const float* wf = w + (h * 16 + fcol) * 288 + kq * 8;
#pragma unroll
        for (int s = 0; s < 9; ++s) {
            float4 lo = reinterpret_cast<const float4*>(wf + s * 32)[0];
            float4 hi = reinterpret_cast<const float4*>(wf + s * 32)[1];
            short8 v;
            v[0] = f2bf(lo.x); v[1] = f2bf(lo.y); v[2] = f2bf(lo.z); v[3] = f2bf(lo.w);
            v[4] = f2bf(hi.x); v[5] = f2bf(hi.y); v[6] = f2bf(hi.z); v[7] = f2bf(hi.w);
            bfr[h][s] = v;
        }
    }
    const float4 bias0 = reinterpret_cast<const float4*>(bias)[kq];
    const float4 bias1 = reinterpret_cast<const float4*>(bias)[4 + kq];

    // ---- work decode, XCD-bijective (256 = 8 x 32): each XCD owns 2 images ----
    const int bid  = blockIdx.x;
    const int sbid = (bid & 7) * 32 + (bid >> 3);
    const int W    = sbid * 8 + wave;      // 0..2047 wave-strip id
    const int b    = W >> 7;               // image (128 strips each)
    const int rem  = W & 127;
    const int cst  = rem >> 5;             // col strip 0..3
    const int rst  = rem & 31;             // row strip 0..31
    const int c0   = cst * 64;
    const int gr0  = rst * RPW;
    const int nck  = (cst < 3) ? 4 : 2;    // strip 3: cols 192..221 -> 2 chunks

    // two NAMED stage register sets (static parity; never addressable)
    float4 svA[NSG], svB[NSG];

#define SLOAD(RR, SET)                                                        \
    {                                                                         \
        int ir_ = gr0 + (RR); if (ir_ > HIN - 1) ir_ = HIN - 1;               \
        _Pragma("unroll")                                                     \
        for (int i_ = 0; i_ < NSG; ++i_) {                                    \
            int g_ = lane + 64 * i_; if (g_ > 527) g_ = 527;                  \
            int px_ = g_ >> 3, sub_ = g_ & 7;                                 \
            int ic_ = c0 + px_; if (ic_ > WIN - 1) ic_ = WIN - 1;             \
            sv##SET[i_] = *reinterpret_cast<const float4*>(                   \
                x + ((b * HIN + ir_) * WIN + ic_) * CIN + sub_ * 4);          \
        }                                                                     \
    }

#define SWRITE(RR, SET)                                                       \
    {                                                                         \
        char* sb_ = wbase + ((RR) & 3) * WROWB;                               \
        _Pragma("unroll")                                                     \
        for (int i_ = 0; i_ < NSG; ++i_) {                                    \
            int g_ = lane + 64 * i_; if (g_ > 527) g_ = 527;                  \
            int px_ = g_ >> 3, sub_ = g_ & 7;                                 \
            uint4 u_ = __builtin_bit_cast(uint4, sv##SET[i_]);                \
            uint2 p_;                                                         \
            p_.x = __builtin_amdgcn_perm(u_.y, u_.x, 0x07060302u);            \
            p_.y = __builtin_amdgcn_perm(u_.w, u_.z, 0x07060302u);            \
            *reinterpret_cast<uint2*>(sb_ + px_ * 64 + sub_ * 8) = p_;        \
        }                                                                     \
    }

#define COMPUTE(R)                                                            \
    {                                                                         \
        const int ho_ = gr0 + (R);                                            \
        _Pragma("unroll")                                                     \
        for (int ck_ = 0; ck_ < 4; ++ck_) {                                   \
            if (ck_ < nck) {                                                  \
                float4v a0_ = {0.f, 0.f, 0.f, 0.f};                           \
                float4v a1_ = {0.f, 0.f, 0.f, 0.f};                           \
                _Pragma("unroll")                                             \
                for (int s_ = 0; s_ < 9; ++s_) {                              \
                    const int kh_ = s_ / 3, kw_ = s_ % 3;                     \
                    const short8 a_ = *reinterpret_cast<const short8*>(       \
                        wbase + (((R) + kh_) & 3) * WROWB +                   \
                        (ck_ * 16 + fcol + kw_) * 64 + kq * 16);              \
                    a0_ = __builtin_amdgcn_mfma_f32_16x16x32_bf16(            \
                        bfr[0][s_], a_, a0_, 0, 0, 0);                        \
                    a1_ = __builtin_amdgcn_mfma_f32_16x16x32_bf16(            \
                        bfr[1][s_], a_, a1_, 0, 0, 0);                        \
                }                                                             \
                const int wo_ = c0 + ck_ * 16 + fcol;                         \
                if (ho_ < HO && wo_ < WO) {                                   \
                    float* o_ = out + ((b * HO + ho_) * WO + wo_) * FOUT;     \
                    float4 v0_ = {a0_[0] + bias0.x, a0_[1] + bias0.y,         \
                                  a0_[2] + bias0.z, a0_[3] + bias0.w};        \
                    float4 v1_ = {a1_[0] + bias1.x, a1_[1] + bias1.y,         \
                                  a1_[2] + bias1.z, a1_[3] + bias1.w};        \
                    reinterpret_cast<float4*>(o_)[kq]     = v0_;              \
                    reinterpret_cast<float4*>(o_)[4 + kq] = v1_;              \
                }                                                             \
            }                                                                 \
        }                                                                     \
    }

#define SB __builtin_amdgcn_sched_barrier(0)

    // ---------- prologue: rows 0..3; parity = row&1 (even->A, odd->B) ----------
    SLOAD(0, A); SLOAD(1, B);
    SWRITE(0, A); SWRITE(1, B);
    SLOAD(2, A); SLOAD(3, B);
    SWRITE(2, A);
    // live: svB = row 3 (written at end of iter 0)

    // ---------- main loop, manual x2 unroll for static reg-set parity ----------
#pragma unroll 1
    for (int r = 0; r < RPW; r += 2) {
        // ---- even iter r: load->A, write<-B ----
        if (r + 4 <= RPW + 1) SLOAD(r + 4, A);   // rows 4,6,8 (even)
        SB;
        COMPUTE(r);
        SB;
        if (r + 3 <= RPW + 1) SWRITE(r + 3, B);  // rows 3,5,7 (odd)
        SB;
        // ---- odd iter r+1: load->B, write<-A ----
        if (r + 1 < RPW) {
            if (r + 5 <= RPW + 1) SLOAD(r + 5, B);   // rows 5,7 (odd)
            SB;
            COMPUTE(r + 1);
            SB;
            if (r + 4 <= RPW + 1) SWRITE(r + 4, A);  // rows 4,6,8 (even)
            SB;
        }
    }
#undef SLOAD
#undef SWRITE
#undef COMPUTE
#undef SB
}

extern "C" void kernel_launch(void* const* d_in, const int* in_sizes, int n_in,
                              void* d_out, int out_size, void* d_ws, size_t ws_size,
                              hipStream_t stream) {
    const float* x    = (const float*)d_in[0];
    const float* w    = (const float*)d_in[1];
    const float* bias = (const float*)d_in[2];
    float* out        = (float*)d_out;

    conv3x3_wave<<<dim3(256), dim3(512), 0, stream>>>(x, w, bias, out);
}

// Round 22
// 45.430 us; speedup vs baseline: 1.2518x; 1.0568x over previous
//
#include <hip/hip_runtime.h>

// Conv2D 3x3 VALID NHWC, B=16 H=W=224 C=32 F=32 -> [16,222,222,32] fp32.
// FINAL (R14 structure; best of 21 rounds: 45.6us timed, 12.7x over naive).
// Wave-autonomous strips -- LDS staging WITHOUT barriers:
//  - 2048 waves each own a 64x7 output strip with a PRIVATE 4-row bf16 LDS
//    ring. Per row r: SLOAD(r+3)->regs | MFMA compute(r) from ring |
//    perm-pack + ds_write(r+3). No s_barrier; in-wave program order +
//    compiler waitcnts are the only sync.
//  - im2col GEMM per 16-px chunk: D[filter][pixel] = mfma_16x16x32_bf16(W,X)
//    (operand-swapped so each lane owns 4 consecutive filters of one pixel
//    -> two contiguous float4 stores; WRITE_SIZE = ideal 98.5 MB).
//  - 64B/px unpadded rows: bank-verified conflict-free for both the b128
//    fragment read and the b64 stage write.
//  - XCD-bijective work remap: each XCD owns 2 whole images -> vertical
//    halo reuse stays in its private L2 (FETCH ~65 MB ~= ideal).
// Closed paths (hard walls, measured): depth-2 staging (128-VGPR cap ->
// spill, R15/R21); >2 waves/SIMD (wave-slot packing at 128 VGPR, R16-R20);
// barriered producer/consumer (50-55us plateau, R8/R9/R12); no-LDS direct
// (latency-bound, R13). 45.6us = 1.75x the 26us HBM floor.

#define HO 222
#define WO 222
#define HIN 224
#define WIN 224
#define CIN 32
#define FOUT 32

#define RPW 7                 // output rows per wave-strip (32 strips x 7 >= 222)
#define WROWB 4224            // 66 px * 64 B bf16 (unpadded -- conflict-free)
#define WAVELDS 16896         // 4 ring slots
#define NSG 9                 // stage granule-iters per lane (528/64 -> 9)

typedef __attribute__((ext_vector_type(8))) short short8;
typedef __attribute__((ext_vector_type(4))) float float4v;

__device__ inline short f2bf(float f) {                  // RNE (weights only)
    unsigned u = __builtin_bit_cast(unsigned, f);
    unsigned r = (u + 0x7FFFu + ((u >> 16) & 1u)) >> 16;
    return (short)r;
}

__global__ __launch_bounds__(512, 2) void conv3x3_wave(
    const float* __restrict__ x,     // [16,224,224,32]
    const float* __restrict__ w,     // [32][288 = (kh,kw,c)]
    const float* __restrict__ bias,  // [32]
    float* __restrict__ out)         // [16,222,222,32]
{
    __shared__ uint4 lds_all[8 * WAVELDS / 16];          // 135168 B
    const int tid  = threadIdx.x;
    const int lane = tid & 63;
    const int wave = tid >> 6;                           // 0..7
    char* wbase = reinterpret_cast<char*>(lds_all) + wave * WAVELDS;

    const int fcol = lane & 15;            // A row (filter) / D col (pixel)
    const int kq   = lane >> 4;            // k-slice: channels kq*8..+7

    // ---- weights -> register A-fragments ----
    short8 bfr[2][9];
#pragma unroll
    for (int h = 0; h < 2; ++h) {
        const float* wf = w + (h * 16 + fcol) * 288 + kq * 8;
#pragma unroll
        for (int s = 0; s < 9; ++s) {
            float4 lo = reinterpret_cast<const float4*>(wf + s * 32)[0];
            float4 hi = reinterpret_cast<const float4*>(wf + s * 32)[1];
            short8 v;
            v[0] = f2bf(lo.x); v[1] = f2bf(lo.y); v[2] = f2bf(lo.z); v[3] = f2bf(lo.w);
            v[4] = f2bf(hi.x); v[5] = f2bf(hi.y); v[6] = f2bf(hi.z); v[7] = f2bf(hi.w);
            bfr[h][s] = v;
        }
    }
    const float4 bias0 = reinterpret_cast<const float4*>(bias)[kq];
    const float4 bias1 = reinterpret_cast<const float4*>(bias)[4 + kq];

    // ---- work decode, XCD-bijective (256 = 8 x 32): each XCD owns 2 images ----
    const int bid  = blockIdx.x;
    const int sbid = (bid & 7) * 32 + (bid >> 3);
    const int W    = sbid * 8 + wave;      // 0..2047 wave-strip id
    const int b    = W >> 7;               // image (128 strips each)
    const int rem  = W & 127;
    const int cst  = rem >> 5;             // col strip 0..3
    const int rst  = rem & 31;             // row strip 0..31
    const int c0   = cst * 64;
    const int gr0  = rst * RPW;
    const int nck  = (cst < 3) ? 4 : 2;    // strip 3 covers cols 192..221

    float4 sv[NSG];                        // stage registers (const-indexed only)

    // stage input row gr0+RR (66 px fp32) into regs
#define SLOAD(RR)                                                             \
    {                                                                         \
        int ir_ = gr0 + (RR); if (ir_ > HIN - 1) ir_ = HIN - 1;               \
        _Pragma("unroll")                                                     \
        for (int i_ = 0; i_ < NSG; ++i_) {                                    \
            int g_ = lane + 64 * i_; if (g_ > 527) g_ = 527;                  \
            int px_ = g_ >> 3, sub_ = g_ & 7;                                 \
            int ic_ = c0 + px_; if (ic_ > WIN - 1) ic_ = WIN - 1;             \
            sv[i_] = *reinterpret_cast<const float4*>(                        \
                x + ((b * HIN + ir_) * WIN + ic_) * CIN + sub_ * 4);          \
        }                                                                     \
    }

    // pack to bf16, write into ring slot (RR)&3
#define SWRITE(RR)                                                            \
    {                                                                         \
        char* sb_ = wbase + ((RR) & 3) * WROWB;                               \
        _Pragma("unroll")                                                     \
        for (int i_ = 0; i_ < NSG; ++i_) {                                    \
            int g_ = lane + 64 * i_; if (g_ > 527) g_ = 527;                  \
            int px_ = g_ >> 3, sub_ = g_ & 7;                                 \
            uint4 u_ = __builtin_bit_cast(uint4, sv[i_]);                     \
            uint2 p_;                                                         \
            p_.x = __builtin_amdgcn_perm(u_.y, u_.x, 0x07060302u);            \
            p_.y = __builtin_amdgcn_perm(u_.w, u_.z, 0x07060302u);            \
            *reinterpret_cast<uint2*>(sb_ + px_ * 64 + sub_ * 8) = p_;        \
        }                                                                     \
    }

    // ---------- prologue: rows 0,1,2 into the ring ----------
    SLOAD(0); SWRITE(0);
    SLOAD(1); SWRITE(1);
    SLOAD(2); SWRITE(2);

    // ---------- barrier-free main loop ----------
#pragma unroll 1
    for (int r = 0; r < RPW; ++r) {
        if (r < RPW - 1) SLOAD(r + 3);               // rows 3..8, in flight over compute
        __builtin_amdgcn_sched_barrier(0);           // don't sink loads into compute

        const int ho = gr0 + r;
#pragma unroll
        for (int ck = 0; ck < 4; ++ck) {
            if (ck < nck) {
                float4v acc0 = {0.f, 0.f, 0.f, 0.f};
                float4v acc1 = {0.f, 0.f, 0.f, 0.f};
#pragma unroll
                for (int s = 0; s < 9; ++s) {
                    const int kh = s / 3, kw = s % 3;
                    const short8 a = *reinterpret_cast<const short8*>(
                        wbase + ((r + kh) & 3) * WROWB + (ck * 16 + fcol + kw) * 64 + kq * 16);
                    acc0 = __builtin_amdgcn_mfma_f32_16x16x32_bf16(bfr[0][s], a, acc0, 0, 0, 0);
                    acc1 = __builtin_amdgcn_mfma_f32_16x16x32_bf16(bfr[1][s], a, acc1, 0, 0, 0);
                }
                // D[filter][pixel]: col(lane&15)=pixel, row=kq*4+r=filter
                const int wo = c0 + ck * 16 + fcol;
                if (ho < HO && wo < WO) {
                    float* o = out + ((b * HO + ho) * WO + wo) * FOUT;
                    float4 v0 = {acc0[0] + bias0.x, acc0[1] + bias0.y,
                                 acc0[2] + bias0.z, acc0[3] + bias0.w};
                    float4 v1 = {acc1[0] + bias1.x, acc1[1] + bias1.y,
                                 acc1[2] + bias1.z, acc1[3] + bias1.w};
                    reinterpret_cast<float4*>(o)[kq]     = v0;
                    reinterpret_cast<float4*>(o)[4 + kq] = v1;
                }
            }
        }

        __builtin_amdgcn_sched_barrier(0);           // keep perms/writes after compute
        if (r < RPW - 1) SWRITE(r + 3);              // slot (r+3)&3 disjoint from read slots
    }
}

extern "C" void kernel_launch(void* const* d_in, const int* in_sizes, int n_in,
                              void* d_out, int out_size, void* d_ws, size_t ws_size,
                              hipStream_t stream) {
    const float* x    = (const float*)d_in[0];
    const float* w    = (const float*)d_in[1];
    const float* bias = (const float*)d_in[2];
    float* out        = (float*)d_out;

    conv3x3_wave<<<dim3(256), dim3(512), 0, stream>>>(x, w, bias, out);
}